// Round 3
// baseline (312.596 us; speedup 1.0000x reference)
//
#include <hip/hip_runtime.h>
#include <cstdint>

#define GRIDW   40
#define SEQ     1600      // 40*40
#define NVOCAB  32
#define PATH_ID 6
#define IGNORE_ID (-100)
#define NWORDS  25        // 1600 / 64
#define BLK     256

// ---------------------------------------------------------------------------
// One block per batch row.
// Phase 1: 8 lanes cooperate per token. Lane l loads float4 = 4 vocab entries;
//   a wave's 64 lanes cover 8 tokens = 1KB contiguous (perfect coalescing,
//   VGPR-resident, zero LDS staging, zero barriers). Argmax + sum-exp reduce
//   via 3-step __shfl_xor butterfly within the 8-lane group. 50 independent
//   iterations/thread -> deep ILP for HBM latency hiding.
// Phase 2: spatial penalty over consecutive path positions + connected
//   components via LDS min-label propagation (unchanged, exact), one
//   atomicAdd per row.
// ---------------------------------------------------------------------------
__global__ __launch_bounds__(BLK) void act_loss_kernel(
    const float* __restrict__ logits,   // [B, SEQ, NVOCAB]
    const int*   __restrict__ labels,   // [B, SEQ]
    const float* __restrict__ qhalt,    // [B]
    float*       __restrict__ out,      // [1]
    int B)
{
    const int b    = blockIdx.x;
    const int tid  = threadIdx.x;
    const int wave = tid >> 6;
    const int lane = tid & 63;
    const int grp  = lane >> 3;          // token subgroup within wave (0..7)
    const int q    = lane & 7;           // vocab-quad index within token (0..7)

    __shared__ uint8_t  path[SEQ];
    __shared__ uint16_t lab[SEQ];
    __shared__ uint16_t pos[SEQ];
    __shared__ uint64_t words[NWORDS];
    __shared__ int      offs[NWORDS + 1];
    __shared__ float    red_f[BLK];
    __shared__ int      red_i[BLK];
    __shared__ int      red_j[BLK];
    __shared__ int      npath_s;
    __shared__ int      changed;
    __shared__ float    part_a;

    // ---------------- Phase 1: per-token CE / argmax, 8 lanes/token --------
    float ce_sum = 0.0f;
    int   cnt = 0, cor = 0;

    const float4* base4 = (const float4*)(logits + (size_t)b * SEQ * NVOCAB);
    const int*    lbase = labels + (size_t)b * SEQ;

    // 1600 tokens / (4 waves * 8 tokens) = 50 iterations
#pragma unroll 2
    for (int it = 0; it < SEQ / 32; ++it) {
        const int   t = it * 32 + wave * 8 + grp;          // this group's token
        const float4 v = base4[it * 256 + wave * 64 + lane]; // wave: 1KB contiguous
        const int   lbl = lbase[t];                         // 8 lanes share a dword

        // local argmax over 4 entries (strict > keeps first occurrence)
        float m = v.x; int a = q * 4;
        if (v.y > m) { m = v.y; a = q * 4 + 1; }
        if (v.z > m) { m = v.z; a = q * 4 + 2; }
        if (v.w > m) { m = v.w; a = q * 4 + 3; }

        // 8-lane butterfly max with min-index tiebreak
#pragma unroll
        for (int d = 1; d <= 4; d <<= 1) {
            float om = __shfl_xor(m, d);
            int   oa = __shfl_xor(a, d);
            if (om > m || (om == m && oa < a)) { m = om; a = oa; }
        }

        // local sum-exp + label pick, then butterfly sum
        const int  slbl = (lbl < 0) ? 0 : lbl;
        float s  = __expf(v.x - m) + __expf(v.y - m)
                 + __expf(v.z - m) + __expf(v.w - m);
        float xl = 0.0f;
        xl = (q * 4 + 0 == slbl) ? v.x : xl;
        xl = (q * 4 + 1 == slbl) ? v.y : xl;
        xl = (q * 4 + 2 == slbl) ? v.z : xl;
        xl = (q * 4 + 3 == slbl) ? v.w : xl;
#pragma unroll
        for (int d = 1; d <= 4; d <<= 1) {
            s  += __shfl_xor(s, d);
            xl += __shfl_xor(xl, d);
        }

        if (q == 0) {                    // group leader records the token
            const bool msk = (lbl != IGNORE_ID);
            const float ce = (m + __logf(s)) - xl;
            ce_sum += msk ? ce : 0.0f;
            cnt    += msk ? 1 : 0;
            cor    += (msk && a == lbl) ? 1 : 0;
            path[t] = (a == PATH_ID) ? 1 : 0;
        }
    }
    __syncthreads();

    // ---------------- block reductions: ce_sum, cnt, cor ----------------
    red_f[tid] = ce_sum; red_i[tid] = cnt; red_j[tid] = cor;
    __syncthreads();
    for (int s = BLK / 2; s > 0; s >>= 1) {
        if (tid < s) {
            red_f[tid] += red_f[tid + s];
            red_i[tid] += red_i[tid + s];
            red_j[tid] += red_j[tid + s];
        }
        __syncthreads();
    }
    if (tid == 0) {
        float ce_tot = red_f[0];
        int   c_tot  = red_i[0];
        int   k_tot  = red_j[0];
        float lm = ce_tot / (float)max(c_tot, 1);
        float t  = (k_tot == c_tot) ? 1.0f : 0.0f;
        float xq = qhalt[b];
        float bce = fmaxf(xq, 0.0f) - xq * t + log1pf(expf(-fabsf(xq)));
        part_a = lm + 0.5f * bce;
    }
    __syncthreads();

    // ---------------- spatial penalty ----------------
    if (tid < NWORDS) {
        uint64_t w = 0;
        int basei = tid * 64;
#pragma unroll 8
        for (int k = 0; k < 64; ++k)
            w |= ((uint64_t)path[basei + k]) << k;
        words[tid] = w;
    }
    __syncthreads();
    if (tid == 0) {
        int o = 0;
        for (int t2 = 0; t2 < NWORDS; ++t2) { offs[t2] = o; o += __popcll(words[t2]); }
        npath_s = o;
    }
    __syncthreads();
    if (tid < NWORDS) {
        int o = offs[tid];
        uint64_t w = words[tid];
        int basei = tid * 64;
        while (w) {
            int k = __ffsll((unsigned long long)w) - 1;
            pos[o++] = (uint16_t)(basei + k);
            w &= (w - 1);
        }
    }
    __syncthreads();

    const int np = npath_s;
    int sp_units = 0;
    for (int p = tid; p + 1 < np; p += BLK) {
        int i = pos[p], j = pos[p + 1];
        int dist = abs(i / GRIDW - j / GRIDW) + abs(i % GRIDW - j % GRIDW);
        if (dist > 1) sp_units += dist - 1;
    }

    // ---------------- connectivity: min-label propagation ----------------
    for (int i = tid; i < SEQ; i += BLK)
        lab[i] = path[i] ? (uint16_t)i : (uint16_t)0xFFFF;
    __syncthreads();

    for (;;) {
        if (tid == 0) changed = 0;
        __syncthreads();
        int local = 0;
        for (int i = tid; i < SEQ; i += BLK) {
            if (!path[i]) continue;
            int r = i / GRIDW, c = i % GRIDW;
            uint16_t v = lab[i];
            uint16_t nm = v;
            if (r > 0)          { uint16_t u = lab[i - GRIDW]; nm = (u < nm) ? u : nm; }
            if (r < GRIDW - 1)  { uint16_t u = lab[i + GRIDW]; nm = (u < nm) ? u : nm; }
            if (c > 0)          { uint16_t u = lab[i - 1];     nm = (u < nm) ? u : nm; }
            if (c < GRIDW - 1)  { uint16_t u = lab[i + 1];     nm = (u < nm) ? u : nm; }
            if (nm < v) { lab[i] = nm; local = 1; }
        }
        if (local) changed = 1;   // benign race: all writers write 1
        __syncthreads();
        if (!changed) break;
    }

    int comp = 0;
    for (int i = tid; i < SEQ; i += BLK)
        comp += (path[i] && lab[i] == (uint16_t)i) ? 1 : 0;

    // reduce sp_units and comp
    red_i[tid] = sp_units; red_j[tid] = comp;
    __syncthreads();
    for (int s = BLK / 2; s > 0; s >>= 1) {
        if (tid < s) {
            red_i[tid] += red_i[tid + s];
            red_j[tid] += red_j[tid + s];
        }
        __syncthreads();
    }

    if (tid == 0) {
        int sp_tot   = red_i[0];
        int comp_tot = red_j[0];
        int conn_units = (comp_tot > 1) ? (comp_tot - 1) : 0;
        float total = part_a +
                      ((float)sp_tot * 10.0f + (float)conn_units * 5.0f) / (float)B;
        atomicAdd(out, total);
    }
}

extern "C" void kernel_launch(void* const* d_in, const int* in_sizes, int n_in,
                              void* d_out, int out_size, void* d_ws, size_t ws_size,
                              hipStream_t stream) {
    const float* logits = (const float*)d_in[0];
    const int*   labels = (const int*)d_in[1];
    const float* qhalt  = (const float*)d_in[2];
    // d_in[3] = halted, d_in[4] = steps: metrics-only in reference, unused.
    float* out = (float*)d_out;
    const int B = in_sizes[2];   // q_halt_logits length = batch

    hipMemsetAsync(out, 0, (size_t)out_size * sizeof(float), stream);
    act_loss_kernel<<<dim3(B), dim3(BLK), 0, stream>>>(logits, labels, qhalt, out, B);
}